// Round 1
// baseline (1464.204 us; speedup 1.0000x reference)
//
#include <hip/hip_runtime.h>
#include <cstdint>
#include <cstddef>

#define BB 256
#define TT 4096
#define ID 63
#define HH 50
#define FCD 64

__device__ __forceinline__ float readlane_f(float v, int lane) {
    return __int_as_float(__builtin_amdgcn_readlane(__float_as_int(v), lane));
}

__device__ __forceinline__ float fast_tanh(float x) {
    // tanh(x) = sign(x) * (1 - e) / (1 + e),  e = exp(-2|x|)  (no overflow, e<=1)
    float a = fabsf(x);
    float e = __builtin_amdgcn_exp2f(a * -2.88539008177792681472f); // -2*log2(e)
    float r = (1.0f - e) * __builtin_amdgcn_rcpf(1.0f + e);
    return copysignf(r, x);
}

// ---------------- Phase 1: z[b,t,j] = b_ih[j] + b_hh[j] + sum_i x[b,t,i]*W_ih[j,i]
// One wave (64 threads) per block; block handles 64 consecutive (b,t) rows.
__global__ __launch_bounds__(64) void proj_kernel(
    const float* __restrict__ x, const float* __restrict__ W_ih,
    const float* __restrict__ b_ih, const float* __restrict__ b_hh,
    float* __restrict__ z)
{
    __shared__ float xs[64 * ID];
    const int lane = threadIdx.x;
    const int64_t row0 = (int64_t)blockIdx.x * 64;
    const float* __restrict__ xin = x + row0 * ID;

    // coalesced stage of 64 rows (16128 B contiguous) into LDS
#pragma unroll
    for (int i = lane; i < 64 * ID; i += 64) xs[i] = xin[i];
    __syncthreads();

    float xr[ID];
#pragma unroll
    for (int i = 0; i < ID; ++i) xr[i] = xs[lane * ID + i];

    float* __restrict__ zout = z + (row0 + lane) * HH;
#pragma unroll 2
    for (int j = 0; j < HH; ++j) {
        float a0 = b_ih[j] + b_hh[j], a1 = 0.f, a2 = 0.f, a3 = 0.f;
#pragma unroll
        for (int i = 0; i < 60; i += 4) {
            a0 += xr[i + 0] * W_ih[j * ID + i + 0];
            a1 += xr[i + 1] * W_ih[j * ID + i + 1];
            a2 += xr[i + 2] * W_ih[j * ID + i + 2];
            a3 += xr[i + 3] * W_ih[j * ID + i + 3];
        }
        a0 += xr[60] * W_ih[j * ID + 60];
        a1 += xr[61] * W_ih[j * ID + 61];
        a2 += xr[62] * W_ih[j * ID + 62];
        zout[j] = (a0 + a2) + (a1 + a3);
    }
}

// ---------------- Phase 2: sequential recurrence, one wave per batch element.
// FUSED=0: zx = precomputed z (biases folded). FUSED=1: zx = x, project on the fly.
template <int FUSED>
__global__ __launch_bounds__(64) void rnn_kernel(
    const float* __restrict__ zx, const float* __restrict__ W_ih,
    const float* __restrict__ b_ih, const float* __restrict__ W_hh,
    const float* __restrict__ b_hh, const float* __restrict__ W1,
    const float* __restrict__ b1, const float* __restrict__ W2,
    const float* __restrict__ b2, float* __restrict__ out)
{
    const int b = blockIdx.x;
    const int lane = threadIdx.x;
    const int j = (lane < HH) ? lane : (HH - 1);

    float whh[HH];
#pragma unroll
    for (int k = 0; k < HH; ++k) whh[k] = W_hh[j * HH + k];

    float wih[FUSED ? ID : 1];
    float bias = 0.f;
    const float* __restrict__ base;
    int col, ld;
    if (FUSED) {
#pragma unroll
        for (int i = 0; i < ID; ++i) wih[i] = W_ih[j * ID + i];
        bias = b_ih[j] + b_hh[j];
        base = zx + (int64_t)b * TT * ID;
        ld = ID;
        col = (lane < ID) ? lane : (ID - 1);
    } else {
        base = zx + (int64_t)b * TT * HH;
        ld = HH;
        col = j;
    }

    // software pipeline the per-step row loads 8 deep (1 wave/CU: no TLP to hide HBM)
    float zp[8], zn[8];
#pragma unroll
    for (int u = 0; u < 8; ++u) zp[u] = base[u * ld + col];

    float vh = 0.f;
    for (int t0 = 0; t0 < TT; t0 += 8) {
#pragma unroll
        for (int u = 0; u < 8; ++u) {
            int tt = t0 + 8 + u;
            if (tt > TT - 1) tt = TT - 1; // clamp: final chunk reloads last row (unused)
            zn[u] = base[(int64_t)tt * ld + col];
        }
#pragma unroll
        for (int u = 0; u < 8; ++u) {
            float a0, a1, a2, a3;
            if (FUSED) {
                a0 = bias; a1 = 0.f; a2 = 0.f; a3 = 0.f;
#pragma unroll
                for (int i = 0; i < 60; i += 4) {
                    a0 += readlane_f(zp[u], i + 0) * wih[i + 0];
                    a1 += readlane_f(zp[u], i + 1) * wih[i + 1];
                    a2 += readlane_f(zp[u], i + 2) * wih[i + 2];
                    a3 += readlane_f(zp[u], i + 3) * wih[i + 3];
                }
                a0 += readlane_f(zp[u], 60) * wih[60];
                a1 += readlane_f(zp[u], 61) * wih[61];
                a2 += readlane_f(zp[u], 62) * wih[62];
            } else {
                a0 = zp[u]; a1 = 0.f; a2 = 0.f; a3 = 0.f;
            }
#pragma unroll
            for (int k = 0; k < 48; k += 4) {
                a0 += readlane_f(vh, k + 0) * whh[k + 0];
                a1 += readlane_f(vh, k + 1) * whh[k + 1];
                a2 += readlane_f(vh, k + 2) * whh[k + 2];
                a3 += readlane_f(vh, k + 3) * whh[k + 3];
            }
            a0 += readlane_f(vh, 48) * whh[48];
            a1 += readlane_f(vh, 49) * whh[49];
            vh = fast_tanh((a0 + a2) + (a1 + a3));
        }
#pragma unroll
        for (int u = 0; u < 8; ++u) zp[u] = zn[u];
    }

    // ---- MLP head + argmax (softmax is monotone; np.argmax tie -> index 0, so strict >)
    float f = b1[lane];
#pragma unroll
    for (int k = 0; k < HH; ++k) f += readlane_f(vh, k) * W1[lane * HH + k];
    f = fmaxf(f, 0.f);
    float p0 = f * W2[lane];
    float p1 = f * W2[FCD + lane];
#pragma unroll
    for (int off = 32; off > 0; off >>= 1) {
        p0 += __shfl_down(p0, off, 64);
        p1 += __shfl_down(p1, off, 64);
    }
    if (lane == 0) out[b] = ((p1 + b2[1]) > (p0 + b2[0])) ? 1.0f : 0.0f;
}

extern "C" void kernel_launch(void* const* d_in, const int* in_sizes, int n_in,
                              void* d_out, int out_size, void* d_ws, size_t ws_size,
                              hipStream_t stream)
{
    const float* x    = (const float*)d_in[0];
    const float* W_ih = (const float*)d_in[1];
    const float* b_ih = (const float*)d_in[2];
    const float* W_hh = (const float*)d_in[3];
    const float* b_hh = (const float*)d_in[4];
    const float* W1   = (const float*)d_in[5];
    const float* b1   = (const float*)d_in[6];
    const float* W2   = (const float*)d_in[7];
    const float* b2   = (const float*)d_in[8];
    float* out = (float*)d_out;

    const size_t zbytes = (size_t)BB * TT * HH * sizeof(float);
    if (ws_size >= zbytes) {
        float* z = (float*)d_ws;
        proj_kernel<<<(BB * TT) / 64, 64, 0, stream>>>(x, W_ih, b_ih, b_hh, z);
        rnn_kernel<0><<<BB, 64, 0, stream>>>(z, W_ih, b_ih, W_hh, b_hh,
                                             W1, b1, W2, b2, out);
    } else {
        rnn_kernel<1><<<BB, 64, 0, stream>>>(x, W_ih, b_ih, W_hh, b_hh,
                                             W1, b1, W2, b2, out);
    }
}

// Round 2
// 1359.371 us; speedup vs baseline: 1.0771x; 1.0771x over previous
//
#include <hip/hip_runtime.h>
#include <cstdint>
#include <cstddef>

#define BB 256
#define TT 4096
#define ID 63
#define HH 50
#define FCD 64

typedef float f32x2 __attribute__((ext_vector_type(2)));

__device__ __forceinline__ uint32_t rl_u32(float v, int lane) {
    return (uint32_t)__builtin_amdgcn_readlane(__float_as_int(v), lane);
}
__device__ __forceinline__ float rl_f(float v, int lane) {
    return __int_as_float(__builtin_amdgcn_readlane(__float_as_int(v), lane));
}

// D = S0 * S1 (packed fp32); hp is a 64-bit SGPR pair holding (h[2k], h[2k+1])
__device__ __forceinline__ f32x2 pk_mul(uint64_t hp, f32x2 w) {
    f32x2 d;
    asm("v_pk_mul_f32 %0, %1, %2" : "=v"(d) : "s"(hp), "v"(w));
    return d;
}
// acc += hp * w (packed fp32, SGPR-pair broadcast operand)
__device__ __forceinline__ void pk_fma(f32x2& acc, uint64_t hp, f32x2 w) {
    asm("v_pk_fma_f32 %0, %1, %2, %0" : "+v"(acc) : "s"(hp), "v"(w));
}

__device__ __forceinline__ float fast_tanh(float x) {
    // tanh(x) = 1 - 2/(e^{2x}+1); exp2 overflow -> inf -> rcp -> 0 (correct +/-1 limits)
    float e = __builtin_amdgcn_exp2f(x * 2.88539008177792681472f); // 2*log2(e)
    return 1.0f - 2.0f * __builtin_amdgcn_rcpf(e + 1.0f);
}

// ---------------- Phase 1: z[b,t,j] = b_ih[j] + b_hh[j] + sum_i x[b,t,i]*W_ih[j,i]
// One wave per block, 64 rows per block. W row via uniform (scalar) loads;
// stores staged through LDS for coalescing.
__global__ __launch_bounds__(64) void proj_kernel(
    const float* __restrict__ x, const float* __restrict__ W_ih,
    const float* __restrict__ b_ih, const float* __restrict__ b_hh,
    float* __restrict__ z)
{
    __shared__ float xs[64 * ID]; // 16128 B; reused as output staging (3200 floats)
    const int lane = threadIdx.x;
    const int64_t row0 = (int64_t)blockIdx.x * 64;

    // coalesced float4 stage of 64 rows (16128 B contiguous)
    const float4* __restrict__ xin4 = (const float4*)(x + row0 * ID);
    float4* xs4 = (float4*)xs;
    for (int i = lane; i < (64 * ID) / 4; i += 64) xs4[i] = xin4[i];
    __syncthreads();

    float xr[ID];
#pragma unroll
    for (int i = 0; i < ID; ++i) xr[i] = xs[lane * ID + i];
    __syncthreads(); // xs re-used as output staging below

    float* zs = xs;
#pragma unroll 1
    for (int j = 0; j < HH; ++j) {
        const float* __restrict__ wp = W_ih + j * ID; // uniform address -> s_load
        float a0 = b_ih[j] + b_hh[j], a1 = 0.f, a2 = 0.f, a3 = 0.f;
#pragma unroll
        for (int i = 0; i < 60; i += 4) {
            a0 = fmaf(xr[i + 0], wp[i + 0], a0);
            a1 = fmaf(xr[i + 1], wp[i + 1], a1);
            a2 = fmaf(xr[i + 2], wp[i + 2], a2);
            a3 = fmaf(xr[i + 3], wp[i + 3], a3);
        }
        a0 = fmaf(xr[60], wp[60], a0);
        a1 = fmaf(xr[61], wp[61], a1);
        a2 = fmaf(xr[62], wp[62], a2);
        zs[lane * HH + j] = (a0 + a2) + (a1 + a3);
    }
    __syncthreads();

    // coalesced write-out: 64 rows x 50 floats = 12800 B contiguous
    const float2* zs2 = (const float2*)zs;
    float2* __restrict__ zo2 = (float2*)(z + row0 * HH);
#pragma unroll
    for (int i = lane; i < (64 * HH) / 2; i += 64) zo2[i] = zs2[i];
}

// ---------------- Phase 2: sequential recurrence, one wave per batch element.
// Packed-fp32 matvec: 25 v_pk_fma_f32 with SGPR-pair broadcast of (h[2k],h[2k+1]).
__global__ __launch_bounds__(64) void rnn_kernel(
    const float* __restrict__ z, const float* __restrict__ W_hh,
    const float* __restrict__ W1, const float* __restrict__ b1,
    const float* __restrict__ W2, const float* __restrict__ b2,
    float* __restrict__ out)
{
    const int b = blockIdx.x;
    const int lane = threadIdx.x;
    const int j = (lane < HH) ? lane : (HH - 1);

    f32x2 wpk[25];
#pragma unroll
    for (int k = 0; k < 25; ++k) {
        wpk[k].x = W_hh[j * HH + 2 * k];
        wpk[k].y = W_hh[j * HH + 2 * k + 1];
    }

    const float* __restrict__ base = z + (int64_t)b * TT * HH;
    const int col = j;

    float zp[8], zn[8];
#pragma unroll
    for (int u = 0; u < 8; ++u) zp[u] = base[u * HH + col];
    const float* p = base + 8 * HH;

    float vh = 0.f;
    for (int t0 = 0; t0 < TT; t0 += 8) {
        if (t0 + 8 < TT) { // uniform branch; last chunk has nothing to prefetch
#pragma unroll
            for (int u = 0; u < 8; ++u) zn[u] = p[u * HH + col];
        }
        p += 8 * HH;
#pragma unroll
        for (int u = 0; u < 8; ++u) {
            uint64_t hp[25];
#pragma unroll
            for (int k = 0; k < 25; ++k) {
                uint32_t lo = rl_u32(vh, 2 * k);
                uint32_t hi = rl_u32(vh, 2 * k + 1);
                hp[k] = (uint64_t)lo | ((uint64_t)hi << 32);
            }
            f32x2 accA = pk_mul(hp[0], wpk[0]);
            f32x2 accB = pk_mul(hp[1], wpk[1]);
#pragma unroll
            for (int k = 2; k < 25; k += 2) pk_fma(accA, hp[k], wpk[k]);
#pragma unroll
            for (int k = 3; k < 25; k += 2) pk_fma(accB, hp[k], wpk[k]);
            f32x2 ab = accA + accB;                 // v_pk_add_f32
            float s = zp[u] + (ab.x + ab.y);
            vh = fast_tanh(s);
        }
#pragma unroll
        for (int u = 0; u < 8; ++u) zp[u] = zn[u];
    }

    // ---- MLP head + argmax (softmax monotone; np.argmax tie -> 0, so strict >)
    float f = b1[lane];
#pragma unroll
    for (int k = 0; k < HH; ++k) f = fmaf(rl_f(vh, k), W1[lane * HH + k], f);
    f = fmaxf(f, 0.f);
    float p0 = f * W2[lane];
    float p1 = f * W2[FCD + lane];
#pragma unroll
    for (int off = 32; off > 0; off >>= 1) {
        p0 += __shfl_down(p0, off, 64);
        p1 += __shfl_down(p1, off, 64);
    }
    if (lane == 0) out[b] = ((p1 + b2[1]) > (p0 + b2[0])) ? 1.0f : 0.0f;
}

// ---------------- Fallback: fully fused (used only if d_ws can't hold z)
__global__ __launch_bounds__(64) void rnn_fused_kernel(
    const float* __restrict__ x, const float* __restrict__ W_ih,
    const float* __restrict__ b_ih, const float* __restrict__ W_hh,
    const float* __restrict__ b_hh, const float* __restrict__ W1,
    const float* __restrict__ b1, const float* __restrict__ W2,
    const float* __restrict__ b2, float* __restrict__ out)
{
    const int b = blockIdx.x;
    const int lane = threadIdx.x;
    const int j = (lane < HH) ? lane : (HH - 1);

    float whh[HH];
#pragma unroll
    for (int k = 0; k < HH; ++k) whh[k] = W_hh[j * HH + k];
    float wih[ID];
#pragma unroll
    for (int i = 0; i < ID; ++i) wih[i] = W_ih[j * ID + i];
    const float bias = b_ih[j] + b_hh[j];

    const float* __restrict__ base = x + (int64_t)b * TT * ID;
    const int col = (lane < ID) ? lane : (ID - 1);

    float zp[8], zn[8];
#pragma unroll
    for (int u = 0; u < 8; ++u) zp[u] = base[u * ID + col];

    float vh = 0.f;
    for (int t0 = 0; t0 < TT; t0 += 8) {
        if (t0 + 8 < TT) {
#pragma unroll
            for (int u = 0; u < 8; ++u) zn[u] = base[(int64_t)(t0 + 8 + u) * ID + col];
        }
#pragma unroll
        for (int u = 0; u < 8; ++u) {
            float a0 = bias, a1 = 0.f, a2 = 0.f, a3 = 0.f;
#pragma unroll
            for (int i = 0; i < 60; i += 4) {
                a0 = fmaf(rl_f(zp[u], i + 0), wih[i + 0], a0);
                a1 = fmaf(rl_f(zp[u], i + 1), wih[i + 1], a1);
                a2 = fmaf(rl_f(zp[u], i + 2), wih[i + 2], a2);
                a3 = fmaf(rl_f(zp[u], i + 3), wih[i + 3], a3);
            }
            a0 = fmaf(rl_f(zp[u], 60), wih[60], a0);
            a1 = fmaf(rl_f(zp[u], 61), wih[61], a1);
            a2 = fmaf(rl_f(zp[u], 62), wih[62], a2);
#pragma unroll
            for (int k = 0; k < 48; k += 4) {
                a0 = fmaf(rl_f(vh, k + 0), whh[k + 0], a0);
                a1 = fmaf(rl_f(vh, k + 1), whh[k + 1], a1);
                a2 = fmaf(rl_f(vh, k + 2), whh[k + 2], a2);
                a3 = fmaf(rl_f(vh, k + 3), whh[k + 3], a3);
            }
            a0 = fmaf(rl_f(vh, 48), whh[48], a0);
            a1 = fmaf(rl_f(vh, 49), whh[49], a1);
            vh = fast_tanh((a0 + a2) + (a1 + a3));
        }
#pragma unroll
        for (int u = 0; u < 8; ++u) zp[u] = zn[u];
    }

    float f = b1[lane];
#pragma unroll
    for (int k = 0; k < HH; ++k) f = fmaf(rl_f(vh, k), W1[lane * HH + k], f);
    f = fmaxf(f, 0.f);
    float p0 = f * W2[lane];
    float p1 = f * W2[FCD + lane];
#pragma unroll
    for (int off = 32; off > 0; off >>= 1) {
        p0 += __shfl_down(p0, off, 64);
        p1 += __shfl_down(p1, off, 64);
    }
    if (lane == 0) out[b] = ((p1 + b2[1]) > (p0 + b2[0])) ? 1.0f : 0.0f;
}

extern "C" void kernel_launch(void* const* d_in, const int* in_sizes, int n_in,
                              void* d_out, int out_size, void* d_ws, size_t ws_size,
                              hipStream_t stream)
{
    const float* x    = (const float*)d_in[0];
    const float* W_ih = (const float*)d_in[1];
    const float* b_ih = (const float*)d_in[2];
    const float* W_hh = (const float*)d_in[3];
    const float* b_hh = (const float*)d_in[4];
    const float* W1   = (const float*)d_in[5];
    const float* b1   = (const float*)d_in[6];
    const float* W2   = (const float*)d_in[7];
    const float* b2   = (const float*)d_in[8];
    float* out = (float*)d_out;

    const size_t zbytes = (size_t)BB * TT * HH * sizeof(float);
    if (ws_size >= zbytes) {
        float* z = (float*)d_ws;
        proj_kernel<<<(BB * TT) / 64, 64, 0, stream>>>(x, W_ih, b_ih, b_hh, z);
        rnn_kernel<<<BB, 64, 0, stream>>>(z, W_hh, W1, b1, W2, b2, out);
    } else {
        rnn_fused_kernel<<<BB, 64, 0, stream>>>(x, W_ih, b_ih, W_hh, b_hh,
                                                W1, b1, W2, b2, out);
    }
}